// Round 6
// baseline (363.103 us; speedup 1.0000x reference)
//
#include <hip/hip_runtime.h>

#define N_NODES 20000
#define N_EDGES 320000
#define ET (N_EDGES + N_NODES)   // 340000 edges incl self-loops
#define F_IN 1024
#define HC 256                   // H*C for layers 1,2
#define NC 4

typedef unsigned short ushort_t;
typedef __attribute__((ext_vector_type(8))) short short8;
typedef __attribute__((ext_vector_type(4))) float f32x4;

// bf16 <-> f32 via bit ops (RTNE)
__device__ inline ushort_t f2bf(float f) {
    unsigned u = __float_as_uint(f);
    unsigned r = (u + 0x7fffu + ((u >> 16) & 1u)) >> 16;
    return (ushort_t)r;
}
__device__ inline float bf2f(ushort_t u) {
    return __uint_as_float(((unsigned)u) << 16);
}

#define GLOAD16(gp, lp) __builtin_amdgcn_global_load_lds( \
    (const __attribute__((address_space(1))) void*)(gp),  \
    (__attribute__((address_space(3))) void*)(lp), 16, 0, 0)

// ---------------- CSR build ----------------
__global__ void count_kernel(const int* __restrict__ ei, int* __restrict__ counts) {
    int e = blockIdx.x * blockDim.x + threadIdx.x;
    if (e >= ET) return;
    int dst = (e < N_EDGES) ? ei[N_EDGES + e] : (e - N_EDGES);
    atomicAdd(&counts[dst], 1);
}

__global__ void scan_kernel(const int* __restrict__ counts, int* __restrict__ row_ptr,
                            int* __restrict__ cursor) {
    __shared__ int sums[1024];
    int t = threadIdx.x;
    const int per = (N_NODES + 1023) / 1024;
    int b = t * per;
    int e = min(b + per, N_NODES);
    int s = 0;
    for (int i = b; i < e; ++i) s += counts[i];
    sums[t] = s;
    __syncthreads();
    for (int off = 1; off < 1024; off <<= 1) {
        int v = (t >= off) ? sums[t - off] : 0;
        __syncthreads();
        sums[t] += v;
        __syncthreads();
    }
    int run = (t == 0) ? 0 : sums[t - 1];
    for (int i = b; i < e; ++i) {
        row_ptr[i] = run;
        cursor[i]  = run;
        run += counts[i];
    }
    if (t == 0) row_ptr[N_NODES] = ET;
}

__global__ void scatter_kernel(const int* __restrict__ ei, int* __restrict__ cursor,
                               int* __restrict__ col) {
    int e = blockIdx.x * blockDim.x + threadIdx.x;
    if (e >= ET) return;
    int src, dst;
    if (e < N_EDGES) { src = ei[e]; dst = ei[N_EDGES + e]; }
    else             { src = dst = e - N_EDGES; }
    int pos = atomicAdd(&cursor[dst], 1);
    col[pos] = src;
}

// ---------------- split fp32 -> bf16 hi/lo ----------------
__global__ void split_rows(const float* __restrict__ in, ushort_t* __restrict__ hi,
                           ushort_t* __restrict__ lo, int n4) {
    int i = blockIdx.x * blockDim.x + threadIdx.x;
    int stride = gridDim.x * blockDim.x;
    for (; i < n4; i += stride) {
        float4 v = ((const float4*)in)[i];
        ushort4 h, l;
        h.x = f2bf(v.x); l.x = f2bf(v.x - bf2f(h.x));
        h.y = f2bf(v.y); l.y = f2bf(v.y - bf2f(h.y));
        h.z = f2bf(v.z); l.z = f2bf(v.z - bf2f(h.z));
        h.w = f2bf(v.w); l.w = f2bf(v.w - bf2f(h.w));
        ((ushort4*)hi)[i] = h;
        ((ushort4*)lo)[i] = l;
    }
}

// weights: in [K][Nn] fp32 row-major -> hi/lo W^T [Nn][K] bf16
__global__ void split_T(const float* __restrict__ in, ushort_t* __restrict__ hi,
                        ushort_t* __restrict__ lo, int K, int Nn) {
    int idx = blockIdx.x * blockDim.x + threadIdx.x;
    if (idx >= K * Nn) return;
    int k = idx / Nn, n = idx - k * Nn;
    float v = in[idx];
    ushort_t h = f2bf(v);
    hi[(size_t)n * K + k] = h;
    lo[(size_t)n * K + k] = f2bf(v - bf2f(h));
}

// ---------------- fused split-bf16 MFMA GEMM, XCD-swizzled 1D grid ----------------
template<int BM, int BN, int GY>
__launch_bounds__(256)
__global__ void gemm_mfma(const ushort_t* __restrict__ Ah, const ushort_t* __restrict__ Al,
                          const ushort_t* __restrict__ BTh, const ushort_t* __restrict__ BTl,
                          float* __restrict__ C, int M, int K, int NT) {
    constexpr int SM = BM / 2;
    constexpr int SN = BN / 2;
    constexpr int MF = SM / 16;
    constexpr int NF = SN / 16;
    constexpr int AQ = BM / 64;
    constexpr int BQ = BN / 64;
    __shared__ __align__(16) ushort_t smem[(2 * BM + 2 * BN) * 32];
    char* Ash = (char*)smem;
    char* Asl = Ash + BM * 64;
    char* Bsh = Asl + BM * 64;
    char* Bsl = Bsh + BN * 64;

    const int t = threadIdx.x, lane = t & 63, w = t >> 6;
    const int wm = w >> 1, wn = w & 1;
    const int nwg = gridDim.x;
    const int id = blockIdx.x;
    const int q = nwg >> 3, r = nwg & 7;
    const int xcd = id & 7, idx = id >> 3;
    const int logical = (xcd < r ? xcd * (q + 1) : r * (q + 1) + (xcd - r) * q) + idx;
    const int bm = (logical / GY) * BM, bn = (logical % GY) * BN;
    const int gchunk = ((lane & 3) ^ ((lane >> 3) & 3)) * 16;  // pre-swizzled source

    size_t gA[AQ]; int lA[AQ];
    #pragma unroll
    for (int qq = 0; qq < AQ; ++qq) {
        int inst = w * AQ + qq;
        int row  = inst * 16 + (lane >> 2);
        int grow = min(bm + row, M - 1);
        gA[qq] = (size_t)grow * K * 2 + gchunk;
        lA[qq] = inst * 1024;
    }
    size_t gB[BQ]; int lB[BQ];
    #pragma unroll
    for (int qq = 0; qq < BQ; ++qq) {
        int inst = w * BQ + qq;
        int row  = inst * 16 + (lane >> 2);
        gB[qq] = (size_t)(bn + row) * K * 2 + gchunk;
        lB[qq] = inst * 1024;
    }

    f32x4 acc[MF][NF];
    #pragma unroll
    for (int i = 0; i < MF; ++i)
        #pragma unroll
        for (int j = 0; j < NF; ++j) acc[i][j] = (f32x4){0.f, 0.f, 0.f, 0.f};

    const char* Ahb = (const char*)Ah;
    const char* Alb = (const char*)Al;
    const char* Bhb = (const char*)BTh;
    const char* Blb = (const char*)BTl;
    const int c16 = (lane >> 4);

    for (int k0 = 0; k0 < K; k0 += 32) {
        size_t kb = (size_t)k0 * 2;
        #pragma unroll
        for (int qq = 0; qq < AQ; ++qq) {
            GLOAD16(Ahb + gA[qq] + kb, Ash + lA[qq]);
            GLOAD16(Alb + gA[qq] + kb, Asl + lA[qq]);
        }
        #pragma unroll
        for (int qq = 0; qq < BQ; ++qq) {
            GLOAD16(Bhb + gB[qq] + kb, Bsh + lB[qq]);
            GLOAD16(Blb + gB[qq] + kb, Bsl + lB[qq]);
        }
        __syncthreads();
        short8 afh[MF], afl[MF], bfh[NF], bfl[NF];
        #pragma unroll
        for (int i = 0; i < MF; ++i) {
            int row = wm * SM + i * 16 + (lane & 15);
            int off = row * 64 + ((c16 ^ ((row >> 1) & 3)) * 16);
            afh[i] = *(const short8*)(Ash + off);
            afl[i] = *(const short8*)(Asl + off);
        }
        #pragma unroll
        for (int j = 0; j < NF; ++j) {
            int row = wn * SN + j * 16 + (lane & 15);
            int off = row * 64 + ((c16 ^ ((row >> 1) & 3)) * 16);
            bfh[j] = *(const short8*)(Bsh + off);
            bfl[j] = *(const short8*)(Bsl + off);
        }
        #pragma unroll
        for (int i = 0; i < MF; ++i)
            #pragma unroll
            for (int j = 0; j < NF; ++j) {
                acc[i][j] = __builtin_amdgcn_mfma_f32_16x16x32_bf16(afh[i], bfh[j], acc[i][j], 0, 0, 0);
                acc[i][j] = __builtin_amdgcn_mfma_f32_16x16x32_bf16(afh[i], bfl[j], acc[i][j], 0, 0, 0);
                acc[i][j] = __builtin_amdgcn_mfma_f32_16x16x32_bf16(afl[i], bfh[j], acc[i][j], 0, 0, 0);
            }
        __syncthreads();
    }
    #pragma unroll
    for (int i = 0; i < MF; ++i) {
        int rbase = bm + wm * SM + i * 16 + (lane >> 4) * 4;
        #pragma unroll
        for (int j = 0; j < NF; ++j) {
            int col = bn + wn * SN + j * 16 + (lane & 15);
            #pragma unroll
            for (int rr = 0; rr < 4; ++rr)
                if (rbase + rr < M) C[(size_t)(rbase + rr) * NT + col] = acc[i][j][rr];
        }
    }
}

// ---------------- attention logits ----------------
template<int H>
__global__ void al_kernel(const float* __restrict__ h, const float* __restrict__ as_w,
                          const float* __restrict__ ad_w, float* __restrict__ als,
                          float* __restrict__ ald) {
    int n = blockIdx.x;
    int t = threadIdx.x;
    float hv = h[(size_t)n * (H * 64) + t];
    float s = hv * as_w[t];
    float d = hv * ad_w[t];
    #pragma unroll
    for (int off = 32; off > 0; off >>= 1) {
        s += __shfl_down(s, off, 64);
        d += __shfl_down(d, off, 64);
    }
    if ((t & 63) == 0) {
        int head = t >> 6;
        als[n * H + head] = s;
        ald[n * H + head] = d;
    }
}

// ---------------- alpha precompute: segment softmax -> alpha[H][ET] ----------------
// one wave per dst (4 dst/block); lanes = (edge-slot, head)
template<int H>
__launch_bounds__(256)
__global__ void alpha_kernel(const float* __restrict__ als, const float* __restrict__ ald,
                             const int* __restrict__ row_ptr, const int* __restrict__ col,
                             float* __restrict__ alpha) {
    int lane = threadIdx.x & 63, w = threadIdx.x >> 6;
    int dst = blockIdx.x * 4 + w;
    if (dst >= N_NODES) return;
    int beg = row_ptr[dst], deg = row_ptr[dst + 1] - beg;
    constexpr int ES = 64 / H;
    int i_loc = lane / H, hh = lane % H;
    float ad = ald[dst * H + hh];
    float m = -1e30f, den = 0.f;
    for (int base = 0; base < deg; base += ES) {
        int i = base + i_loc;
        if (i < deg) {
            float e = als[col[beg + i] * H + hh] + ad;
            e = (e > 0.f) ? e : 0.2f * e;
            float nm = fmaxf(m, e);
            den = den * __expf(m - nm) + __expf(e - nm);
            m = nm;
        }
    }
    #pragma unroll
    for (int off = H; off < 64; off <<= 1) {
        float mo = __shfl_xor(m, off, 64);
        float dn = __shfl_xor(den, off, 64);
        float nm = fmaxf(m, mo);
        den = den * __expf(m - nm) + dn * __expf(mo - nm);
        m = nm;
    }
    float rden = 1.f / (den + 1e-16f);
    for (int base = 0; base < deg; base += ES) {
        int i = base + i_loc;
        if (i < deg) {
            float e = als[col[beg + i] * H + hh] + ad;
            e = (e > 0.f) ? e : 0.2f * e;
            alpha[(size_t)hh * ET + beg + i] = __expf(e - m) * rden;
        }
    }
}

// ---------------- channel-sliced aggregation ----------------
// CT channels total, NS slices of 32 channels; grid = NS*5000 blocks slice-major,
// m204-swizzled so slice s lives on XCD s*8/NS -> per-XCD L2 working set 2.56 MB.
// 4 waves/block = 4 dst; 8 teams of 8 lanes per wave; team gathers 128 B rows.
template<int CT, int NS, int H, bool RELU, bool SPLIT>
__launch_bounds__(256)
__global__ void agg_sliced(const float* __restrict__ h, const float* __restrict__ alpha,
                           const int* __restrict__ row_ptr, const int* __restrict__ col,
                           const float* __restrict__ bias,
                           ushort_t* __restrict__ oh, ushort_t* __restrict__ ol,
                           float* __restrict__ of) {
    constexpr int CW = CT / NS;              // 32 channels per slice
    const int nwg = gridDim.x;               // NS*5000, multiple of 8
    const int q = nwg >> 3;
    int id = blockIdx.x;
    int logical = (id & 7) * q + (id >> 3);
    int slice = logical / (N_NODES / 4);
    int g = logical % (N_NODES / 4);
    int lane = threadIdx.x & 63, w = threadIdx.x >> 6;
    int dst = g * 4 + w;
    int c = lane & 7, team = lane >> 3;
    int beg = row_ptr[dst], deg = row_ptr[dst + 1] - beg;
    const float* alphaS = alpha + (size_t)(slice * H / NS) * ET;
    const float* hS = h + slice * CW;

    float4 acc  = make_float4(0.f, 0.f, 0.f, 0.f);
    float4 acc2 = make_float4(0.f, 0.f, 0.f, 0.f);
    int e = team;
    for (; e + 8 < deg; e += 16) {
        int   s0 = col[beg + e],        s1 = col[beg + e + 8];
        float a0 = alphaS[beg + e],     a1 = alphaS[beg + e + 8];
        float4 h0 = *(const float4*)&hS[(size_t)s0 * CT + c * 4];
        float4 h1 = *(const float4*)&hS[(size_t)s1 * CT + c * 4];
        acc.x  += a0 * h0.x; acc.y  += a0 * h0.y; acc.z  += a0 * h0.z; acc.w  += a0 * h0.w;
        acc2.x += a1 * h1.x; acc2.y += a1 * h1.y; acc2.z += a1 * h1.z; acc2.w += a1 * h1.w;
    }
    if (e < deg) {
        int   s0 = col[beg + e];
        float a0 = alphaS[beg + e];
        float4 h0 = *(const float4*)&hS[(size_t)s0 * CT + c * 4];
        acc.x += a0 * h0.x; acc.y += a0 * h0.y; acc.z += a0 * h0.z; acc.w += a0 * h0.w;
    }
    acc.x += acc2.x; acc.y += acc2.y; acc.z += acc2.z; acc.w += acc2.w;
    #pragma unroll
    for (int off = 8; off < 64; off <<= 1) {
        acc.x += __shfl_xor(acc.x, off, 64);
        acc.y += __shfl_xor(acc.y, off, 64);
        acc.z += __shfl_xor(acc.z, off, 64);
        acc.w += __shfl_xor(acc.w, off, 64);
    }
    if (team == 0) {
        int ch = slice * CW + c * 4;
        float4 bv = *(const float4*)&bias[ch];
        float v0 = acc.x + bv.x, v1 = acc.y + bv.y, v2 = acc.z + bv.z, v3 = acc.w + bv.w;
        if (RELU) {
            v0 = fmaxf(v0, 0.f); v1 = fmaxf(v1, 0.f);
            v2 = fmaxf(v2, 0.f); v3 = fmaxf(v3, 0.f);
        }
        size_t idx = (size_t)dst * CT + ch;
        if (SPLIT) {
            ushort4 h4, l4;
            h4.x = f2bf(v0); l4.x = f2bf(v0 - bf2f(h4.x));
            h4.y = f2bf(v1); l4.y = f2bf(v1 - bf2f(h4.y));
            h4.z = f2bf(v2); l4.z = f2bf(v2 - bf2f(h4.z));
            h4.w = f2bf(v3); l4.w = f2bf(v3 - bf2f(h4.w));
            *(ushort4*)&oh[idx] = h4;
            *(ushort4*)&ol[idx] = l4;
        } else {
            *(float4*)&of[idx] = make_float4(v0, v1, v2, v3);
        }
    }
}

// ---------------- classifier ----------------
__global__ void classifier_kernel(const float* __restrict__ x, const float* __restrict__ wc,
                                  const float* __restrict__ bc, float* __restrict__ out) {
    int n = blockIdx.x * blockDim.x + threadIdx.x;
    if (n >= N_NODES) return;
    float acc[NC] = {bc[0], bc[1], bc[2], bc[3]};
    for (int c = 0; c < 64; ++c) {
        float xv = x[(size_t)n * 64 + c];
        #pragma unroll
        for (int k = 0; k < NC; ++k) acc[k] += xv * wc[c * NC + k];
    }
    #pragma unroll
    for (int k = 0; k < NC; ++k) out[(size_t)n * NC + k] = acc[k];
}

extern "C" void kernel_launch(void* const* d_in, const int* in_sizes, int n_in,
                              void* d_out, int out_size, void* d_ws, size_t ws_size,
                              hipStream_t stream) {
    const float* x   = (const float*)d_in[0];
    const int*   ei  = (const int*)d_in[1];
    const float* w1  = (const float*)d_in[2];
    const float* as1 = (const float*)d_in[3];
    const float* ad1 = (const float*)d_in[4];
    const float* b1  = (const float*)d_in[5];
    const float* w2  = (const float*)d_in[6];
    const float* as2 = (const float*)d_in[7];
    const float* ad2 = (const float*)d_in[8];
    const float* b2  = (const float*)d_in[9];
    const float* w3  = (const float*)d_in[10];
    const float* as3 = (const float*)d_in[11];
    const float* ad3 = (const float*)d_in[12];
    const float* b3  = (const float*)d_in[13];
    const float* wc  = (const float*)d_in[14];
    const float* bc  = (const float*)d_in[15];
    float* out = (float*)d_out;

    char* ws = (char*)d_ws;
    size_t off = 0;
    auto alloc = [&](size_t bytes) -> char* {
        char* p = ws + off;
        off = (off + bytes + 255) & ~(size_t)255;
        return p;
    };

    int* counts  = (int*)alloc(N_NODES * 4);
    int* cursor  = (int*)alloc(N_NODES * 4);
    int* row_ptr = (int*)alloc((N_NODES + 1) * 4);
    int* colidx  = (int*)alloc(ET * 4);
    float* als   = (float*)alloc(N_NODES * 4 * 4);
    float* ald   = (float*)alloc(N_NODES * 4 * 4);
    float* alpha = (float*)alloc((size_t)4 * ET * 4);        // [H][ET]
    float* B0    = (float*)alloc((size_t)N_NODES * HC * 4);

    ushort_t* xh   = (ushort_t*)alloc((size_t)N_NODES * F_IN * 2);
    ushort_t* xl   = (ushort_t*)alloc((size_t)N_NODES * F_IN * 2);
    ushort_t* w1Th = (ushort_t*)alloc((size_t)F_IN * HC * 2);
    ushort_t* w1Tl = (ushort_t*)alloc((size_t)F_IN * HC * 2);
    ushort_t* w2Th = (ushort_t*)alloc((size_t)HC * HC * 2);
    ushort_t* w2Tl = (ushort_t*)alloc((size_t)HC * HC * 2);
    ushort_t* w3Th = (ushort_t*)alloc((size_t)HC * 64 * 2);
    ushort_t* w3Tl = (ushort_t*)alloc((size_t)HC * 64 * 2);
    ushort_t* B1h  = (ushort_t*)alloc((size_t)N_NODES * HC * 2);
    ushort_t* B1l  = (ushort_t*)alloc((size_t)N_NODES * HC * 2);
    float*    B1f  = (float*)alloc((size_t)N_NODES * 64 * 4);

    // ---- CSR build ----
    hipMemsetAsync(counts, 0, N_NODES * sizeof(int), stream);
    int eb = (ET + 255) / 256;
    count_kernel<<<eb, 256, 0, stream>>>(ei, counts);
    scan_kernel<<<1, 1024, 0, stream>>>(counts, row_ptr, cursor);
    scatter_kernel<<<eb, 256, 0, stream>>>(ei, cursor, colidx);

    // ---- precision split ----
    split_rows<<<2048, 256, 0, stream>>>(x, xh, xl, (int)((size_t)N_NODES * F_IN / 4));
    split_T<<<(F_IN * HC + 255) / 256, 256, 0, stream>>>(w1, w1Th, w1Tl, F_IN, HC);
    split_T<<<(HC * HC + 255) / 256, 256, 0, stream>>>(w2, w2Th, w2Tl, HC, HC);
    split_T<<<(HC * 64 + 255) / 256, 256, 0, stream>>>(w3, w3Th, w3Tl, HC, 64);

    const int nwg12 = ((N_NODES + 127) / 128) * (HC / 64);   // 628
    const int nblk_dst = N_NODES / 4;                        // 5000
    // ---- layer 1 ----
    gemm_mfma<128, 64, 4><<<nwg12, 256, 0, stream>>>(xh, xl, w1Th, w1Tl, B0, N_NODES, F_IN, HC);
    al_kernel<4><<<N_NODES, 256, 0, stream>>>(B0, as1, ad1, als, ald);
    alpha_kernel<4><<<nblk_dst, 256, 0, stream>>>(als, ald, row_ptr, colidx, alpha);
    agg_sliced<256, 8, 4, true, true><<<8 * nblk_dst, 256, 0, stream>>>(
        B0, alpha, row_ptr, colidx, b1, B1h, B1l, nullptr);
    // ---- layer 2 ----
    gemm_mfma<128, 64, 4><<<nwg12, 256, 0, stream>>>(B1h, B1l, w2Th, w2Tl, B0, N_NODES, HC, HC);
    al_kernel<4><<<N_NODES, 256, 0, stream>>>(B0, as2, ad2, als, ald);
    alpha_kernel<4><<<nblk_dst, 256, 0, stream>>>(als, ald, row_ptr, colidx, alpha);
    agg_sliced<256, 8, 4, true, true><<<8 * nblk_dst, 256, 0, stream>>>(
        B0, alpha, row_ptr, colidx, b2, B1h, B1l, nullptr);
    // ---- layer 3 (H=1, C=64) ----
    const int nwg3 = (N_NODES + 63) / 64;                    // 313
    gemm_mfma<64, 64, 1><<<nwg3, 256, 0, stream>>>(B1h, B1l, w3Th, w3Tl, B0, N_NODES, HC, 64);
    al_kernel<1><<<N_NODES, 64, 0, stream>>>(B0, as3, ad3, als, ald);
    alpha_kernel<1><<<nblk_dst, 256, 0, stream>>>(als, ald, row_ptr, colidx, alpha);
    agg_sliced<64, 2, 1, false, false><<<2 * nblk_dst, 256, 0, stream>>>(
        B0, alpha, row_ptr, colidx, b3, nullptr, nullptr, B1f);
    // ---- classifier ----
    classifier_kernel<<<(N_NODES + 255) / 256, 256, 0, stream>>>(B1f, wc, bc, out);
}

// Round 8
// 334.796 us; speedup vs baseline: 1.0846x; 1.0846x over previous
//
#include <hip/hip_runtime.h>

#define N_NODES 20000
#define N_EDGES 320000
#define ET (N_EDGES + N_NODES)   // 340000 edges incl self-loops
#define F_IN 1024
#define HC 256                   // H*C for layers 1,2
#define NC 4

typedef unsigned short ushort_t;
typedef __attribute__((ext_vector_type(8))) short short8;
typedef __attribute__((ext_vector_type(4))) float f32x4;

// bf16 <-> f32 via bit ops (RTNE)
__device__ inline ushort_t f2bf(float f) {
    unsigned u = __float_as_uint(f);
    unsigned r = (u + 0x7fffu + ((u >> 16) & 1u)) >> 16;
    return (ushort_t)r;
}
__device__ inline float bf2f(ushort_t u) {
    return __uint_as_float(((unsigned)u) << 16);
}

#define GLOAD16(gp, lp) __builtin_amdgcn_global_load_lds( \
    (const __attribute__((address_space(1))) void*)(gp),  \
    (__attribute__((address_space(3))) void*)(lp), 16, 0, 0)

// ---------------- CSR build ----------------
__global__ void count_kernel(const int* __restrict__ ei, int* __restrict__ counts) {
    int e = blockIdx.x * blockDim.x + threadIdx.x;
    if (e >= ET) return;
    int dst = (e < N_EDGES) ? ei[N_EDGES + e] : (e - N_EDGES);
    atomicAdd(&counts[dst], 1);
}

__global__ void scan_kernel(const int* __restrict__ counts, int* __restrict__ row_ptr,
                            int* __restrict__ cursor) {
    __shared__ int sums[1024];
    int t = threadIdx.x;
    const int per = (N_NODES + 1023) / 1024;
    int b = t * per;
    int e = min(b + per, N_NODES);
    int s = 0;
    for (int i = b; i < e; ++i) s += counts[i];
    sums[t] = s;
    __syncthreads();
    for (int off = 1; off < 1024; off <<= 1) {
        int v = (t >= off) ? sums[t - off] : 0;
        __syncthreads();
        sums[t] += v;
        __syncthreads();
    }
    int run = (t == 0) ? 0 : sums[t - 1];
    for (int i = b; i < e; ++i) {
        row_ptr[i] = run;
        cursor[i]  = run;
        run += counts[i];
    }
    if (t == 0) row_ptr[N_NODES] = ET;
}

__global__ void scatter_kernel(const int* __restrict__ ei, int* __restrict__ cursor,
                               int* __restrict__ col) {
    int e = blockIdx.x * blockDim.x + threadIdx.x;
    if (e >= ET) return;
    int src, dst;
    if (e < N_EDGES) { src = ei[e]; dst = ei[N_EDGES + e]; }
    else             { src = dst = e - N_EDGES; }
    int pos = atomicAdd(&cursor[dst], 1);
    col[pos] = src;
}

// ---------------- split fp32 -> bf16 hi/lo ----------------
__global__ void split_rows(const float* __restrict__ in, ushort_t* __restrict__ hi,
                           ushort_t* __restrict__ lo, int n4) {
    int i = blockIdx.x * blockDim.x + threadIdx.x;
    int stride = gridDim.x * blockDim.x;
    for (; i < n4; i += stride) {
        float4 v = ((const float4*)in)[i];
        ushort4 h, l;
        h.x = f2bf(v.x); l.x = f2bf(v.x - bf2f(h.x));
        h.y = f2bf(v.y); l.y = f2bf(v.y - bf2f(h.y));
        h.z = f2bf(v.z); l.z = f2bf(v.z - bf2f(h.z));
        h.w = f2bf(v.w); l.w = f2bf(v.w - bf2f(h.w));
        ((ushort4*)hi)[i] = h;
        ((ushort4*)lo)[i] = l;
    }
}

// weights: in [K][Nn] fp32 row-major -> hi/lo W^T [Nn][K] bf16
__global__ void split_T(const float* __restrict__ in, ushort_t* __restrict__ hi,
                        ushort_t* __restrict__ lo, int K, int Nn) {
    int idx = blockIdx.x * blockDim.x + threadIdx.x;
    if (idx >= K * Nn) return;
    int k = idx / Nn, n = idx - k * Nn;
    float v = in[idx];
    ushort_t h = f2bf(v);
    hi[(size_t)n * K + k] = h;
    lo[(size_t)n * K + k] = f2bf(v - bf2f(h));
}

// ---------------- fused split-bf16 MFMA GEMM, XCD-swizzled 1D grid ----------------
template<int BM, int BN, int GY>
__launch_bounds__(256)
__global__ void gemm_mfma(const ushort_t* __restrict__ Ah, const ushort_t* __restrict__ Al,
                          const ushort_t* __restrict__ BTh, const ushort_t* __restrict__ BTl,
                          float* __restrict__ C, int M, int K, int NT) {
    constexpr int SM = BM / 2;
    constexpr int SN = BN / 2;
    constexpr int MF = SM / 16;
    constexpr int NF = SN / 16;
    constexpr int AQ = BM / 64;
    constexpr int BQ = BN / 64;
    __shared__ __align__(16) ushort_t smem[(2 * BM + 2 * BN) * 32];
    char* Ash = (char*)smem;
    char* Asl = Ash + BM * 64;
    char* Bsh = Asl + BM * 64;
    char* Bsl = Bsh + BN * 64;

    const int t = threadIdx.x, lane = t & 63, w = t >> 6;
    const int wm = w >> 1, wn = w & 1;
    const int nwg = gridDim.x;
    const int id = blockIdx.x;
    const int q = nwg >> 3, r = nwg & 7;
    const int xcd = id & 7, idx = id >> 3;
    const int logical = (xcd < r ? xcd * (q + 1) : r * (q + 1) + (xcd - r) * q) + idx;
    const int bm = (logical / GY) * BM, bn = (logical % GY) * BN;
    const int gchunk = ((lane & 3) ^ ((lane >> 3) & 3)) * 16;  // pre-swizzled source

    size_t gA[AQ]; int lA[AQ];
    #pragma unroll
    for (int qq = 0; qq < AQ; ++qq) {
        int inst = w * AQ + qq;
        int row  = inst * 16 + (lane >> 2);
        int grow = min(bm + row, M - 1);
        gA[qq] = (size_t)grow * K * 2 + gchunk;
        lA[qq] = inst * 1024;
    }
    size_t gB[BQ]; int lB[BQ];
    #pragma unroll
    for (int qq = 0; qq < BQ; ++qq) {
        int inst = w * BQ + qq;
        int row  = inst * 16 + (lane >> 2);
        gB[qq] = (size_t)(bn + row) * K * 2 + gchunk;
        lB[qq] = inst * 1024;
    }

    f32x4 acc[MF][NF];
    #pragma unroll
    for (int i = 0; i < MF; ++i)
        #pragma unroll
        for (int j = 0; j < NF; ++j) acc[i][j] = (f32x4){0.f, 0.f, 0.f, 0.f};

    const char* Ahb = (const char*)Ah;
    const char* Alb = (const char*)Al;
    const char* Bhb = (const char*)BTh;
    const char* Blb = (const char*)BTl;
    const int c16 = (lane >> 4);

    for (int k0 = 0; k0 < K; k0 += 32) {
        size_t kb = (size_t)k0 * 2;
        #pragma unroll
        for (int qq = 0; qq < AQ; ++qq) {
            GLOAD16(Ahb + gA[qq] + kb, Ash + lA[qq]);
            GLOAD16(Alb + gA[qq] + kb, Asl + lA[qq]);
        }
        #pragma unroll
        for (int qq = 0; qq < BQ; ++qq) {
            GLOAD16(Bhb + gB[qq] + kb, Bsh + lB[qq]);
            GLOAD16(Blb + gB[qq] + kb, Bsl + lB[qq]);
        }
        __syncthreads();
        short8 afh[MF], afl[MF], bfh[NF], bfl[NF];
        #pragma unroll
        for (int i = 0; i < MF; ++i) {
            int row = wm * SM + i * 16 + (lane & 15);
            int off = row * 64 + ((c16 ^ ((row >> 1) & 3)) * 16);
            afh[i] = *(const short8*)(Ash + off);
            afl[i] = *(const short8*)(Asl + off);
        }
        #pragma unroll
        for (int j = 0; j < NF; ++j) {
            int row = wn * SN + j * 16 + (lane & 15);
            int off = row * 64 + ((c16 ^ ((row >> 1) & 3)) * 16);
            bfh[j] = *(const short8*)(Bsh + off);
            bfl[j] = *(const short8*)(Bsl + off);
        }
        #pragma unroll
        for (int i = 0; i < MF; ++i)
            #pragma unroll
            for (int j = 0; j < NF; ++j) {
                acc[i][j] = __builtin_amdgcn_mfma_f32_16x16x32_bf16(afh[i], bfh[j], acc[i][j], 0, 0, 0);
                acc[i][j] = __builtin_amdgcn_mfma_f32_16x16x32_bf16(afh[i], bfl[j], acc[i][j], 0, 0, 0);
                acc[i][j] = __builtin_amdgcn_mfma_f32_16x16x32_bf16(afl[i], bfh[j], acc[i][j], 0, 0, 0);
            }
        __syncthreads();
    }
    #pragma unroll
    for (int i = 0; i < MF; ++i) {
        int rbase = bm + wm * SM + i * 16 + (lane >> 4) * 4;
        #pragma unroll
        for (int j = 0; j < NF; ++j) {
            int col = bn + wn * SN + j * 16 + (lane & 15);
            #pragma unroll
            for (int rr = 0; rr < 4; ++rr)
                if (rbase + rr < M) C[(size_t)(rbase + rr) * NT + col] = acc[i][j][rr];
        }
    }
}

// ---------------- attention logits ----------------
template<int H>
__global__ void al_kernel(const float* __restrict__ h, const float* __restrict__ as_w,
                          const float* __restrict__ ad_w, float* __restrict__ als,
                          float* __restrict__ ald) {
    int n = blockIdx.x;
    int t = threadIdx.x;
    float hv = h[(size_t)n * (H * 64) + t];
    float s = hv * as_w[t];
    float d = hv * ad_w[t];
    #pragma unroll
    for (int off = 32; off > 0; off >>= 1) {
        s += __shfl_down(s, off, 64);
        d += __shfl_down(d, off, 64);
    }
    if ((t & 63) == 0) {
        int head = t >> 6;
        als[n * H + head] = s;
        ald[n * H + head] = d;
    }
}

// ---------------- alpha precompute: segment softmax -> alpha[H][ET] ----------------
template<int H>
__launch_bounds__(256)
__global__ void alpha_kernel(const float* __restrict__ als, const float* __restrict__ ald,
                             const int* __restrict__ row_ptr, const int* __restrict__ col,
                             float* __restrict__ alpha) {
    int lane = threadIdx.x & 63, w = threadIdx.x >> 6;
    int dst = blockIdx.x * 4 + w;
    if (dst >= N_NODES) return;
    int beg = row_ptr[dst], deg = row_ptr[dst + 1] - beg;
    constexpr int ES = 64 / H;
    int i_loc = lane / H, hh = lane % H;
    float ad = ald[dst * H + hh];
    float m = -1e30f, den = 0.f;
    for (int base = 0; base < deg; base += ES) {
        int i = base + i_loc;
        if (i < deg) {
            float e = als[col[beg + i] * H + hh] + ad;
            e = (e > 0.f) ? e : 0.2f * e;
            float nm = fmaxf(m, e);
            den = den * __expf(m - nm) + __expf(e - nm);
            m = nm;
        }
    }
    #pragma unroll
    for (int off = H; off < 64; off <<= 1) {
        float mo = __shfl_xor(m, off, 64);
        float dn = __shfl_xor(den, off, 64);
        float nm = fmaxf(m, mo);
        den = den * __expf(m - nm) + dn * __expf(mo - nm);
        m = nm;
    }
    float rden = 1.f / (den + 1e-16f);
    for (int base = 0; base < deg; base += ES) {
        int i = base + i_loc;
        if (i < deg) {
            float e = als[col[beg + i] * H + hh] + ad;
            e = (e > 0.f) ? e : 0.2f * e;
            alpha[(size_t)hh * ET + beg + i] = __expf(e - m) * rden;
        }
    }
}

// ---------------- channel-sliced aggregation v3 (LDS broadcast) ----------------
// CW=64-channel slices (slice == head for H=4; single slice for H=1).
// Grid slice-major, m204-swizzled -> each slice owns 8/NS XCDs (L2 locality).
// Per wave: one dst; 64 edges' col/alpha loaded lane-parallel then broadcast
// via per-wave LDS (exec-safe; R7's shfl-from-exited-lane bug fixed);
// 4 teams x 16 lanes gather float4 h slices (16 indep loads in flight/wave).
template<int CT, int CW, int H, bool RELU, bool SPLIT>
__launch_bounds__(256)
__global__ void agg_v3(const float* __restrict__ h, const float* __restrict__ alpha,
                       const int* __restrict__ row_ptr, const int* __restrict__ col,
                       const float* __restrict__ bias,
                       ushort_t* __restrict__ oh, ushort_t* __restrict__ ol,
                       float* __restrict__ of) {
    constexpr int NS  = CT / CW;         // slices (== H)
    constexpr int LPT = CW / 4;          // lanes per team (16)
    constexpr int TPW = 64 / LPT;        // teams / edges in flight per wave (4)
    static_assert(NS == H, "slice==head mapping");
    __shared__ int   s_src[4][64];
    __shared__ float s_alp[4][64];
    const int nwg = gridDim.x;           // NS * N/4, multiple of 8
    const int q = nwg >> 3;
    int id = blockIdx.x;
    int logical = (id & 7) * q + (id >> 3);
    int slice = logical / (N_NODES / 4);
    int g = logical - slice * (N_NODES / 4);
    int lane = threadIdx.x & 63, w = threadIdx.x >> 6;
    int dst = g * 4 + w;
    int beg = row_ptr[dst], deg = row_ptr[dst + 1] - beg;
    int team = lane / LPT;
    int cc = (lane & (LPT - 1)) * 4;     // channel quad within slice

    const int*   colP = col + beg;
    const float* aP   = alpha + (size_t)slice * ET + beg;
    const float* hS   = h + slice * CW + cc;

    float4 acc = make_float4(0.f, 0.f, 0.f, 0.f);
    for (int base = 0; base < deg; base += 64) {
        int cnt = min(64, deg - base);
        if (lane < cnt) {
            s_src[w][lane] = colP[base + lane];
            s_alp[w][lane] = aP[base + lane];
        }
        // same-wave LDS write->read: compiler orders via lgkmcnt; no barrier needed
        for (int i = team; i < cnt; i += TPW) {
            int   s = s_src[w][i];
            float a = s_alp[w][i];
            float4 hv = *(const float4*)&hS[s * CT];     // 32-bit addr math
            acc.x += a * hv.x; acc.y += a * hv.y;
            acc.z += a * hv.z; acc.w += a * hv.w;
        }
    }
    #pragma unroll
    for (int off = LPT; off < 64; off <<= 1) {
        acc.x += __shfl_xor(acc.x, off, 64);
        acc.y += __shfl_xor(acc.y, off, 64);
        acc.z += __shfl_xor(acc.z, off, 64);
        acc.w += __shfl_xor(acc.w, off, 64);
    }
    if (team == 0) {
        int ch = slice * CW + cc;
        float4 bv = *(const float4*)&bias[ch];
        float v0 = acc.x + bv.x, v1 = acc.y + bv.y, v2 = acc.z + bv.z, v3 = acc.w + bv.w;
        if (RELU) {
            v0 = fmaxf(v0, 0.f); v1 = fmaxf(v1, 0.f);
            v2 = fmaxf(v2, 0.f); v3 = fmaxf(v3, 0.f);
        }
        size_t idx = (size_t)dst * CT + ch;
        if (SPLIT) {
            ushort4 h4, l4;
            h4.x = f2bf(v0); l4.x = f2bf(v0 - bf2f(h4.x));
            h4.y = f2bf(v1); l4.y = f2bf(v1 - bf2f(h4.y));
            h4.z = f2bf(v2); l4.z = f2bf(v2 - bf2f(h4.z));
            h4.w = f2bf(v3); l4.w = f2bf(v3 - bf2f(h4.w));
            *(ushort4*)&oh[idx] = h4;
            *(ushort4*)&ol[idx] = l4;
        } else {
            *(float4*)&of[idx] = make_float4(v0, v1, v2, v3);
        }
    }
}

// ---------------- classifier ----------------
__global__ void classifier_kernel(const float* __restrict__ x, const float* __restrict__ wc,
                                  const float* __restrict__ bc, float* __restrict__ out) {
    int n = blockIdx.x * blockDim.x + threadIdx.x;
    if (n >= N_NODES) return;
    float acc[NC] = {bc[0], bc[1], bc[2], bc[3]};
    for (int c = 0; c < 64; ++c) {
        float xv = x[(size_t)n * 64 + c];
        #pragma unroll
        for (int k = 0; k < NC; ++k) acc[k] += xv * wc[c * NC + k];
    }
    #pragma unroll
    for (int k = 0; k < NC; ++k) out[(size_t)n * NC + k] = acc[k];
}

extern "C" void kernel_launch(void* const* d_in, const int* in_sizes, int n_in,
                              void* d_out, int out_size, void* d_ws, size_t ws_size,
                              hipStream_t stream) {
    const float* x   = (const float*)d_in[0];
    const int*   ei  = (const int*)d_in[1];
    const float* w1  = (const float*)d_in[2];
    const float* as1 = (const float*)d_in[3];
    const float* ad1 = (const float*)d_in[4];
    const float* b1  = (const float*)d_in[5];
    const float* w2  = (const float*)d_in[6];
    const float* as2 = (const float*)d_in[7];
    const float* ad2 = (const float*)d_in[8];
    const float* b2  = (const float*)d_in[9];
    const float* w3  = (const float*)d_in[10];
    const float* as3 = (const float*)d_in[11];
    const float* ad3 = (const float*)d_in[12];
    const float* b3  = (const float*)d_in[13];
    const float* wc  = (const float*)d_in[14];
    const float* bc  = (const float*)d_in[15];
    float* out = (float*)d_out;

    char* ws = (char*)d_ws;
    size_t off = 0;
    auto alloc = [&](size_t bytes) -> char* {
        char* p = ws + off;
        off = (off + bytes + 255) & ~(size_t)255;
        return p;
    };

    int* counts  = (int*)alloc(N_NODES * 4);
    int* cursor  = (int*)alloc(N_NODES * 4);
    int* row_ptr = (int*)alloc((N_NODES + 1) * 4);
    int* colidx  = (int*)alloc(ET * 4);
    float* als   = (float*)alloc(N_NODES * 4 * 4);
    float* ald   = (float*)alloc(N_NODES * 4 * 4);
    float* alpha = (float*)alloc((size_t)4 * ET * 4);        // [H][ET]
    float* B0    = (float*)alloc((size_t)N_NODES * HC * 4);

    ushort_t* xh   = (ushort_t*)alloc((size_t)N_NODES * F_IN * 2);
    ushort_t* xl   = (ushort_t*)alloc((size_t)N_NODES * F_IN * 2);
    ushort_t* w1Th = (ushort_t*)alloc((size_t)F_IN * HC * 2);
    ushort_t* w1Tl = (ushort_t*)alloc((size_t)F_IN * HC * 2);
    ushort_t* w2Th = (ushort_t*)alloc((size_t)HC * HC * 2);
    ushort_t* w2Tl = (ushort_t*)alloc((size_t)HC * HC * 2);
    ushort_t* w3Th = (ushort_t*)alloc((size_t)HC * 64 * 2);
    ushort_t* w3Tl = (ushort_t*)alloc((size_t)HC * 64 * 2);
    ushort_t* B1h  = (ushort_t*)alloc((size_t)N_NODES * HC * 2);
    ushort_t* B1l  = (ushort_t*)alloc((size_t)N_NODES * HC * 2);
    float*    B1f  = (float*)alloc((size_t)N_NODES * 64 * 4);

    // ---- CSR build ----
    hipMemsetAsync(counts, 0, N_NODES * sizeof(int), stream);
    int eb = (ET + 255) / 256;
    count_kernel<<<eb, 256, 0, stream>>>(ei, counts);
    scan_kernel<<<1, 1024, 0, stream>>>(counts, row_ptr, cursor);
    scatter_kernel<<<eb, 256, 0, stream>>>(ei, cursor, colidx);

    // ---- precision split ----
    split_rows<<<2048, 256, 0, stream>>>(x, xh, xl, (int)((size_t)N_NODES * F_IN / 4));
    split_T<<<(F_IN * HC + 255) / 256, 256, 0, stream>>>(w1, w1Th, w1Tl, F_IN, HC);
    split_T<<<(HC * HC + 255) / 256, 256, 0, stream>>>(w2, w2Th, w2Tl, HC, HC);
    split_T<<<(HC * 64 + 255) / 256, 256, 0, stream>>>(w3, w3Th, w3Tl, HC, 64);

    const int nwg12 = ((N_NODES + 127) / 128) * (HC / 64);   // 628
    const int nblk_dst = N_NODES / 4;                        // 5000
    // ---- layer 1 ----
    gemm_mfma<128, 64, 4><<<nwg12, 256, 0, stream>>>(xh, xl, w1Th, w1Tl, B0, N_NODES, F_IN, HC);
    al_kernel<4><<<N_NODES, 256, 0, stream>>>(B0, as1, ad1, als, ald);
    alpha_kernel<4><<<nblk_dst, 256, 0, stream>>>(als, ald, row_ptr, colidx, alpha);
    agg_v3<256, 64, 4, true, true><<<4 * nblk_dst, 256, 0, stream>>>(
        B0, alpha, row_ptr, colidx, b1, B1h, B1l, nullptr);
    // ---- layer 2 ----
    gemm_mfma<128, 64, 4><<<nwg12, 256, 0, stream>>>(B1h, B1l, w2Th, w2Tl, B0, N_NODES, HC, HC);
    al_kernel<4><<<N_NODES, 256, 0, stream>>>(B0, as2, ad2, als, ald);
    alpha_kernel<4><<<nblk_dst, 256, 0, stream>>>(als, ald, row_ptr, colidx, alpha);
    agg_v3<256, 64, 4, true, true><<<4 * nblk_dst, 256, 0, stream>>>(
        B0, alpha, row_ptr, colidx, b2, B1h, B1l, nullptr);
    // ---- layer 3 (H=1, C=64) ----
    const int nwg3 = (N_NODES + 63) / 64;                    // 313
    gemm_mfma<64, 64, 1><<<nwg3, 256, 0, stream>>>(B1h, B1l, w3Th, w3Tl, B0, N_NODES, HC, 64);
    al_kernel<1><<<N_NODES, 64, 0, stream>>>(B0, as3, ad3, als, ald);
    alpha_kernel<1><<<nblk_dst, 256, 0, stream>>>(als, ald, row_ptr, colidx, alpha);
    agg_v3<64, 64, 1, false, false><<<nblk_dst, 256, 0, stream>>>(
        B0, alpha, row_ptr, colidx, b3, nullptr, nullptr, B1f);
    // ---- classifier ----
    classifier_kernel<<<(N_NODES + 255) / 256, 256, 0, stream>>>(B1f, wc, bc, out);
}

// Round 9
// 316.910 us; speedup vs baseline: 1.1458x; 1.0564x over previous
//
#include <hip/hip_runtime.h>

#define N_NODES 20000
#define N_EDGES 320000
#define ET (N_EDGES + N_NODES)   // 340000 edges incl self-loops
#define F_IN 1024
#define HC 256                   // H*C for layers 1,2
#define NC 4

typedef unsigned short ushort_t;
typedef __attribute__((ext_vector_type(8))) short short8;
typedef __attribute__((ext_vector_type(4))) float f32x4;

// bf16 <-> f32 via bit ops (RTNE)
__device__ inline ushort_t f2bf(float f) {
    unsigned u = __float_as_uint(f);
    unsigned r = (u + 0x7fffu + ((u >> 16) & 1u)) >> 16;
    return (ushort_t)r;
}
__device__ inline float bf2f(ushort_t u) {
    return __uint_as_float(((unsigned)u) << 16);
}

#define GLOAD16(gp, lp) __builtin_amdgcn_global_load_lds( \
    (const __attribute__((address_space(1))) void*)(gp),  \
    (__attribute__((address_space(3))) void*)(lp), 16, 0, 0)

// ---------------- CSR build ----------------
__global__ void count_kernel(const int* __restrict__ ei, int* __restrict__ counts) {
    int e = blockIdx.x * blockDim.x + threadIdx.x;
    if (e >= ET) return;
    int dst = (e < N_EDGES) ? ei[N_EDGES + e] : (e - N_EDGES);
    atomicAdd(&counts[dst], 1);
}

__global__ void scan_kernel(const int* __restrict__ counts, int* __restrict__ row_ptr,
                            int* __restrict__ cursor) {
    __shared__ int sums[1024];
    int t = threadIdx.x;
    const int per = (N_NODES + 1023) / 1024;
    int b = t * per;
    int e = min(b + per, N_NODES);
    int s = 0;
    for (int i = b; i < e; ++i) s += counts[i];
    sums[t] = s;
    __syncthreads();
    for (int off = 1; off < 1024; off <<= 1) {
        int v = (t >= off) ? sums[t - off] : 0;
        __syncthreads();
        sums[t] += v;
        __syncthreads();
    }
    int run = (t == 0) ? 0 : sums[t - 1];
    for (int i = b; i < e; ++i) {
        row_ptr[i] = run;
        cursor[i]  = run;
        run += counts[i];
    }
    if (t == 0) row_ptr[N_NODES] = ET;
}

__global__ void scatter_kernel(const int* __restrict__ ei, int* __restrict__ cursor,
                               int* __restrict__ col) {
    int e = blockIdx.x * blockDim.x + threadIdx.x;
    if (e >= ET) return;
    int src, dst;
    if (e < N_EDGES) { src = ei[e]; dst = ei[N_EDGES + e]; }
    else             { src = dst = e - N_EDGES; }
    int pos = atomicAdd(&cursor[dst], 1);
    col[pos] = src;
}

// weights: in [K][Nn] fp32 row-major -> hi/lo W^T [Nn][K] bf16
__global__ void split_T(const float* __restrict__ in, ushort_t* __restrict__ hi,
                        ushort_t* __restrict__ lo, int K, int Nn) {
    int idx = blockIdx.x * blockDim.x + threadIdx.x;
    if (idx >= K * Nn) return;
    int k = idx / Nn, n = idx - k * Nn;
    float v = in[idx];
    ushort_t h = f2bf(v);
    hi[(size_t)n * K + k] = h;
    lo[(size_t)n * K + k] = f2bf(v - bf2f(h));
}

// ---------------- GEMM1: fp32 A, on-the-fly hi/lo split, 64x64 tile ----------------
// C[M,NT] = x[M,K](f32) @ (Bh+Bl) with split-bf16 3-product accumulation.
// A reg-staged: fp32 -> bf16 h/l in regs -> swizzled ds_write (write pos = chunk^s(row)).
template<int GY>
__launch_bounds__(256)
__global__ void gemm_f32a(const float* __restrict__ X,
                          const ushort_t* __restrict__ BTh, const ushort_t* __restrict__ BTl,
                          float* __restrict__ C, int M, int K, int NT) {
    constexpr int BM = 64, BN = 64, SM = 32, SN = 32, MF = 2, NF = 2;
    __shared__ __align__(16) ushort_t smem[4 * 64 * 32];
    char* Ash = (char*)smem;                  // 4096 B each
    char* Asl = Ash + 64 * 64;
    char* Bsh = Asl + 64 * 64;
    char* Bsl = Bsh + 64 * 64;

    const int t = threadIdx.x, lane = t & 63, w = t >> 6;
    const int wm = w >> 1, wn = w & 1;
    const int nwg = gridDim.x;
    const int id = blockIdx.x;
    const int q = nwg >> 3, r = nwg & 7;
    const int xcd = id & 7, idx = id >> 3;
    const int logical = (xcd < r ? xcd * (q + 1) : r * (q + 1) + (xcd - r) * q) + idx;
    const int bm = (logical / GY) * BM, bn = (logical % GY) * BN;

    // A staging geometry: row = w*16 + lane>>2 (64 rows), chunk = lane&3 (8 bf16)
    const int arow = w * 16 + (lane >> 2);
    const int achk = lane & 3;
    const int grow = min(bm + arow, M - 1);
    const float* xRow = X + (size_t)grow * K + achk * 8;
    const int aoff = arow * 64 + ((achk ^ ((arow >> 1) & 3)) * 16);

    // B staging (gload_lds, pre-swizzled source)
    const int gchunk = ((lane & 3) ^ ((lane >> 3) & 3)) * 16;
    const int brow = w * 16 + (lane >> 2);
    size_t gB = (size_t)(bn + brow) * K * 2 + gchunk;
    int lB = w * 1024;

    f32x4 acc[MF][NF];
    #pragma unroll
    for (int i = 0; i < MF; ++i)
        #pragma unroll
        for (int j = 0; j < NF; ++j) acc[i][j] = (f32x4){0.f, 0.f, 0.f, 0.f};

    const char* Bhb = (const char*)BTh;
    const char* Blb = (const char*)BTl;
    const int c16 = (lane >> 4);

    for (int k0 = 0; k0 < K; k0 += 32) {
        // A: fp32 -> h/l split in regs -> swizzled LDS write
        float4 v0 = *(const float4*)(xRow + k0);
        float4 v1 = *(const float4*)(xRow + k0 + 4);
        ushort_t hh[8], ll[8];
        float vv[8] = {v0.x, v0.y, v0.z, v0.w, v1.x, v1.y, v1.z, v1.w};
        #pragma unroll
        for (int u = 0; u < 8; ++u) {
            hh[u] = f2bf(vv[u]);
            ll[u] = f2bf(vv[u] - bf2f(hh[u]));
        }
        *(short8*)(Ash + aoff) = *(short8*)hh;
        *(short8*)(Asl + aoff) = *(short8*)ll;
        // B: async to LDS
        size_t kb = (size_t)k0 * 2;
        GLOAD16(Bhb + gB + kb, Bsh + lB);
        GLOAD16(Blb + gB + kb, Bsl + lB);
        __syncthreads();
        short8 afh[MF], afl[MF], bfh[NF], bfl[NF];
        #pragma unroll
        for (int i = 0; i < MF; ++i) {
            int row = wm * SM + i * 16 + (lane & 15);
            int off = row * 64 + ((c16 ^ ((row >> 1) & 3)) * 16);
            afh[i] = *(const short8*)(Ash + off);
            afl[i] = *(const short8*)(Asl + off);
        }
        #pragma unroll
        for (int j = 0; j < NF; ++j) {
            int row = wn * SN + j * 16 + (lane & 15);
            int off = row * 64 + ((c16 ^ ((row >> 1) & 3)) * 16);
            bfh[j] = *(const short8*)(Bsh + off);
            bfl[j] = *(const short8*)(Bsl + off);
        }
        #pragma unroll
        for (int i = 0; i < MF; ++i)
            #pragma unroll
            for (int j = 0; j < NF; ++j) {
                acc[i][j] = __builtin_amdgcn_mfma_f32_16x16x32_bf16(afh[i], bfh[j], acc[i][j], 0, 0, 0);
                acc[i][j] = __builtin_amdgcn_mfma_f32_16x16x32_bf16(afh[i], bfl[j], acc[i][j], 0, 0, 0);
                acc[i][j] = __builtin_amdgcn_mfma_f32_16x16x32_bf16(afl[i], bfh[j], acc[i][j], 0, 0, 0);
            }
        __syncthreads();
    }
    #pragma unroll
    for (int i = 0; i < MF; ++i) {
        int rbase = bm + wm * SM + i * 16 + (lane >> 4) * 4;
        #pragma unroll
        for (int j = 0; j < NF; ++j) {
            int col = bn + wn * SN + j * 16 + (lane & 15);
            #pragma unroll
            for (int rr = 0; rr < 4; ++rr)
                if (rbase + rr < M) C[(size_t)(rbase + rr) * NT + col] = acc[i][j][rr];
        }
    }
}

// ---------------- fused split-bf16 MFMA GEMM (bf16 A), XCD-swizzled 1D grid ----------------
template<int BM, int BN, int GY>
__launch_bounds__(256)
__global__ void gemm_mfma(const ushort_t* __restrict__ Ah, const ushort_t* __restrict__ Al,
                          const ushort_t* __restrict__ BTh, const ushort_t* __restrict__ BTl,
                          float* __restrict__ C, int M, int K, int NT) {
    constexpr int SM = BM / 2;
    constexpr int SN = BN / 2;
    constexpr int MF = SM / 16;
    constexpr int NF = SN / 16;
    constexpr int AQ = BM / 64;
    constexpr int BQ = BN / 64;
    __shared__ __align__(16) ushort_t smem[(2 * BM + 2 * BN) * 32];
    char* Ash = (char*)smem;
    char* Asl = Ash + BM * 64;
    char* Bsh = Asl + BM * 64;
    char* Bsl = Bsh + BN * 64;

    const int t = threadIdx.x, lane = t & 63, w = t >> 6;
    const int wm = w >> 1, wn = w & 1;
    const int nwg = gridDim.x;
    const int id = blockIdx.x;
    const int q = nwg >> 3, r = nwg & 7;
    const int xcd = id & 7, idx = id >> 3;
    const int logical = (xcd < r ? xcd * (q + 1) : r * (q + 1) + (xcd - r) * q) + idx;
    const int bm = (logical / GY) * BM, bn = (logical % GY) * BN;
    const int gchunk = ((lane & 3) ^ ((lane >> 3) & 3)) * 16;  // pre-swizzled source

    size_t gA[AQ]; int lA[AQ];
    #pragma unroll
    for (int qq = 0; qq < AQ; ++qq) {
        int inst = w * AQ + qq;
        int row  = inst * 16 + (lane >> 2);
        int grow = min(bm + row, M - 1);
        gA[qq] = (size_t)grow * K * 2 + gchunk;
        lA[qq] = inst * 1024;
    }
    size_t gB[BQ]; int lB[BQ];
    #pragma unroll
    for (int qq = 0; qq < BQ; ++qq) {
        int inst = w * BQ + qq;
        int row  = inst * 16 + (lane >> 2);
        gB[qq] = (size_t)(bn + row) * K * 2 + gchunk;
        lB[qq] = inst * 1024;
    }

    f32x4 acc[MF][NF];
    #pragma unroll
    for (int i = 0; i < MF; ++i)
        #pragma unroll
        for (int j = 0; j < NF; ++j) acc[i][j] = (f32x4){0.f, 0.f, 0.f, 0.f};

    const char* Ahb = (const char*)Ah;
    const char* Alb = (const char*)Al;
    const char* Bhb = (const char*)BTh;
    const char* Blb = (const char*)BTl;
    const int c16 = (lane >> 4);

    for (int k0 = 0; k0 < K; k0 += 32) {
        size_t kb = (size_t)k0 * 2;
        #pragma unroll
        for (int qq = 0; qq < AQ; ++qq) {
            GLOAD16(Ahb + gA[qq] + kb, Ash + lA[qq]);
            GLOAD16(Alb + gA[qq] + kb, Asl + lA[qq]);
        }
        #pragma unroll
        for (int qq = 0; qq < BQ; ++qq) {
            GLOAD16(Bhb + gB[qq] + kb, Bsh + lB[qq]);
            GLOAD16(Blb + gB[qq] + kb, Bsl + lB[qq]);
        }
        __syncthreads();
        short8 afh[MF], afl[MF], bfh[NF], bfl[NF];
        #pragma unroll
        for (int i = 0; i < MF; ++i) {
            int row = wm * SM + i * 16 + (lane & 15);
            int off = row * 64 + ((c16 ^ ((row >> 1) & 3)) * 16);
            afh[i] = *(const short8*)(Ash + off);
            afl[i] = *(const short8*)(Asl + off);
        }
        #pragma unroll
        for (int j = 0; j < NF; ++j) {
            int row = wn * SN + j * 16 + (lane & 15);
            int off = row * 64 + ((c16 ^ ((row >> 1) & 3)) * 16);
            bfh[j] = *(const short8*)(Bsh + off);
            bfl[j] = *(const short8*)(Bsl + off);
        }
        #pragma unroll
        for (int i = 0; i < MF; ++i)
            #pragma unroll
            for (int j = 0; j < NF; ++j) {
                acc[i][j] = __builtin_amdgcn_mfma_f32_16x16x32_bf16(afh[i], bfh[j], acc[i][j], 0, 0, 0);
                acc[i][j] = __builtin_amdgcn_mfma_f32_16x16x32_bf16(afh[i], bfl[j], acc[i][j], 0, 0, 0);
                acc[i][j] = __builtin_amdgcn_mfma_f32_16x16x32_bf16(afl[i], bfh[j], acc[i][j], 0, 0, 0);
            }
        __syncthreads();
    }
    #pragma unroll
    for (int i = 0; i < MF; ++i) {
        int rbase = bm + wm * SM + i * 16 + (lane >> 4) * 4;
        #pragma unroll
        for (int j = 0; j < NF; ++j) {
            int col = bn + wn * SN + j * 16 + (lane & 15);
            #pragma unroll
            for (int rr = 0; rr < 4; ++rr)
                if (rbase + rr < M) C[(size_t)(rbase + rr) * NT + col] = acc[i][j][rr];
        }
    }
}

// ---------------- attention logits ----------------
template<int H>
__global__ void al_kernel(const float* __restrict__ h, const float* __restrict__ as_w,
                          const float* __restrict__ ad_w, float* __restrict__ als,
                          float* __restrict__ ald) {
    int n = blockIdx.x;
    int t = threadIdx.x;
    float hv = h[(size_t)n * (H * 64) + t];
    float s = hv * as_w[t];
    float d = hv * ad_w[t];
    #pragma unroll
    for (int off = 32; off > 0; off >>= 1) {
        s += __shfl_down(s, off, 64);
        d += __shfl_down(d, off, 64);
    }
    if ((t & 63) == 0) {
        int head = t >> 6;
        als[n * H + head] = s;
        ald[n * H + head] = d;
    }
}

// ---------------- alpha precompute: segment softmax -> alpha[H][ET] ----------------
template<int H>
__launch_bounds__(256)
__global__ void alpha_kernel(const float* __restrict__ als, const float* __restrict__ ald,
                             const int* __restrict__ row_ptr, const int* __restrict__ col,
                             float* __restrict__ alpha) {
    int lane = threadIdx.x & 63, w = threadIdx.x >> 6;
    int dst = blockIdx.x * 4 + w;
    if (dst >= N_NODES) return;
    int beg = row_ptr[dst], deg = row_ptr[dst + 1] - beg;
    constexpr int ES = 64 / H;
    int i_loc = lane / H, hh = lane % H;
    float ad = ald[dst * H + hh];
    float m = -1e30f, den = 0.f;
    for (int base = 0; base < deg; base += ES) {
        int i = base + i_loc;
        if (i < deg) {
            float e = als[col[beg + i] * H + hh] + ad;
            e = (e > 0.f) ? e : 0.2f * e;
            float nm = fmaxf(m, e);
            den = den * __expf(m - nm) + __expf(e - nm);
            m = nm;
        }
    }
    #pragma unroll
    for (int off = H; off < 64; off <<= 1) {
        float mo = __shfl_xor(m, off, 64);
        float dn = __shfl_xor(den, off, 64);
        float nm = fmaxf(m, mo);
        den = den * __expf(m - nm) + dn * __expf(mo - nm);
        m = nm;
    }
    float rden = 1.f / (den + 1e-16f);
    for (int base = 0; base < deg; base += ES) {
        int i = base + i_loc;
        if (i < deg) {
            float e = als[col[beg + i] * H + hh] + ad;
            e = (e > 0.f) ? e : 0.2f * e;
            alpha[(size_t)hh * ET + beg + i] = __expf(e - m) * rden;
        }
    }
}

// ---------------- channel-sliced aggregation v3 (LDS broadcast) ----------------
template<int CT, int CW, int H, bool RELU, bool SPLIT>
__launch_bounds__(256)
__global__ void agg_v3(const float* __restrict__ h, const float* __restrict__ alpha,
                       const int* __restrict__ row_ptr, const int* __restrict__ col,
                       const float* __restrict__ bias,
                       ushort_t* __restrict__ oh, ushort_t* __restrict__ ol,
                       float* __restrict__ of) {
    constexpr int NS  = CT / CW;         // slices (== H)
    constexpr int LPT = CW / 4;          // lanes per team (16)
    constexpr int TPW = 64 / LPT;        // teams / edges in flight per wave (4)
    static_assert(NS == H, "slice==head mapping");
    __shared__ int   s_src[4][64];
    __shared__ float s_alp[4][64];
    const int nwg = gridDim.x;           // NS * N/4, multiple of 8
    const int q = nwg >> 3;
    int id = blockIdx.x;
    int logical = (id & 7) * q + (id >> 3);
    int slice = logical / (N_NODES / 4);
    int g = logical - slice * (N_NODES / 4);
    int lane = threadIdx.x & 63, w = threadIdx.x >> 6;
    int dst = g * 4 + w;
    int beg = row_ptr[dst], deg = row_ptr[dst + 1] - beg;
    int team = lane / LPT;
    int cc = (lane & (LPT - 1)) * 4;     // channel quad within slice

    const int*   colP = col + beg;
    const float* aP   = alpha + (size_t)slice * ET + beg;
    const float* hS   = h + slice * CW + cc;

    float4 acc = make_float4(0.f, 0.f, 0.f, 0.f);
    for (int base = 0; base < deg; base += 64) {
        int cnt = min(64, deg - base);
        if (lane < cnt) {
            s_src[w][lane] = colP[base + lane];
            s_alp[w][lane] = aP[base + lane];
        }
        for (int i = team; i < cnt; i += TPW) {
            int   s = s_src[w][i];
            float a = s_alp[w][i];
            float4 hv = *(const float4*)&hS[s * CT];     // 32-bit addr math
            acc.x += a * hv.x; acc.y += a * hv.y;
            acc.z += a * hv.z; acc.w += a * hv.w;
        }
    }
    #pragma unroll
    for (int off = LPT; off < 64; off <<= 1) {
        acc.x += __shfl_xor(acc.x, off, 64);
        acc.y += __shfl_xor(acc.y, off, 64);
        acc.z += __shfl_xor(acc.z, off, 64);
        acc.w += __shfl_xor(acc.w, off, 64);
    }
    if (team == 0) {
        int ch = slice * CW + cc;
        float4 bv = *(const float4*)&bias[ch];
        float v0 = acc.x + bv.x, v1 = acc.y + bv.y, v2 = acc.z + bv.z, v3 = acc.w + bv.w;
        if (RELU) {
            v0 = fmaxf(v0, 0.f); v1 = fmaxf(v1, 0.f);
            v2 = fmaxf(v2, 0.f); v3 = fmaxf(v3, 0.f);
        }
        size_t idx = (size_t)dst * CT + ch;
        if (SPLIT) {
            ushort4 h4, l4;
            h4.x = f2bf(v0); l4.x = f2bf(v0 - bf2f(h4.x));
            h4.y = f2bf(v1); l4.y = f2bf(v1 - bf2f(h4.y));
            h4.z = f2bf(v2); l4.z = f2bf(v2 - bf2f(h4.z));
            h4.w = f2bf(v3); l4.w = f2bf(v3 - bf2f(h4.w));
            *(ushort4*)&oh[idx] = h4;
            *(ushort4*)&ol[idx] = l4;
        } else {
            *(float4*)&of[idx] = make_float4(v0, v1, v2, v3);
        }
    }
}

// ---------------- classifier ----------------
__global__ void classifier_kernel(const float* __restrict__ x, const float* __restrict__ wc,
                                  const float* __restrict__ bc, float* __restrict__ out) {
    int n = blockIdx.x * blockDim.x + threadIdx.x;
    if (n >= N_NODES) return;
    float acc[NC] = {bc[0], bc[1], bc[2], bc[3]};
    for (int c = 0; c < 64; ++c) {
        float xv = x[(size_t)n * 64 + c];
        #pragma unroll
        for (int k = 0; k < NC; ++k) acc[k] += xv * wc[c * NC + k];
    }
    #pragma unroll
    for (int k = 0; k < NC; ++k) out[(size_t)n * NC + k] = acc[k];
}

extern "C" void kernel_launch(void* const* d_in, const int* in_sizes, int n_in,
                              void* d_out, int out_size, void* d_ws, size_t ws_size,
                              hipStream_t stream) {
    const float* x   = (const float*)d_in[0];
    const int*   ei  = (const int*)d_in[1];
    const float* w1  = (const float*)d_in[2];
    const float* as1 = (const float*)d_in[3];
    const float* ad1 = (const float*)d_in[4];
    const float* b1  = (const float*)d_in[5];
    const float* w2  = (const float*)d_in[6];
    const float* as2 = (const float*)d_in[7];
    const float* ad2 = (const float*)d_in[8];
    const float* b2  = (const float*)d_in[9];
    const float* w3  = (const float*)d_in[10];
    const float* as3 = (const float*)d_in[11];
    const float* ad3 = (const float*)d_in[12];
    const float* b3  = (const float*)d_in[13];
    const float* wc  = (const float*)d_in[14];
    const float* bc  = (const float*)d_in[15];
    float* out = (float*)d_out;

    char* ws = (char*)d_ws;
    size_t off = 0;
    auto alloc = [&](size_t bytes) -> char* {
        char* p = ws + off;
        off = (off + bytes + 255) & ~(size_t)255;
        return p;
    };

    int* counts  = (int*)alloc(N_NODES * 4);
    int* cursor  = (int*)alloc(N_NODES * 4);
    int* row_ptr = (int*)alloc((N_NODES + 1) * 4);
    int* colidx  = (int*)alloc(ET * 4);
    float* als   = (float*)alloc(N_NODES * 4 * 4);
    float* ald   = (float*)alloc(N_NODES * 4 * 4);
    float* alpha = (float*)alloc((size_t)4 * ET * 4);        // [H][ET]
    float* B0    = (float*)alloc((size_t)N_NODES * HC * 4);

    ushort_t* w1Th = (ushort_t*)alloc((size_t)F_IN * HC * 2);
    ushort_t* w1Tl = (ushort_t*)alloc((size_t)F_IN * HC * 2);
    ushort_t* w2Th = (ushort_t*)alloc((size_t)HC * HC * 2);
    ushort_t* w2Tl = (ushort_t*)alloc((size_t)HC * HC * 2);
    ushort_t* w3Th = (ushort_t*)alloc((size_t)HC * 64 * 2);
    ushort_t* w3Tl = (ushort_t*)alloc((size_t)HC * 64 * 2);
    ushort_t* B1h  = (ushort_t*)alloc((size_t)N_NODES * HC * 2);
    ushort_t* B1l  = (ushort_t*)alloc((size_t)N_NODES * HC * 2);
    float*    B1f  = (float*)alloc((size_t)N_NODES * 64 * 4);

    // ---- CSR build ----
    hipMemsetAsync(counts, 0, N_NODES * sizeof(int), stream);
    int eb = (ET + 255) / 256;
    count_kernel<<<eb, 256, 0, stream>>>(ei, counts);
    scan_kernel<<<1, 1024, 0, stream>>>(counts, row_ptr, cursor);
    scatter_kernel<<<eb, 256, 0, stream>>>(ei, cursor, colidx);

    // ---- weight precision split ----
    split_T<<<(F_IN * HC + 255) / 256, 256, 0, stream>>>(w1, w1Th, w1Tl, F_IN, HC);
    split_T<<<(HC * HC + 255) / 256, 256, 0, stream>>>(w2, w2Th, w2Tl, HC, HC);
    split_T<<<(HC * 64 + 255) / 256, 256, 0, stream>>>(w3, w3Th, w3Tl, HC, 64);

    const int nwg64 = ((N_NODES + 63) / 64) * (HC / 64);     // 313*4 = 1252
    const int nblk_dst = N_NODES / 4;                        // 5000
    // ---- layer 1 (fp32 A, on-the-fly split) ----
    gemm_f32a<4><<<nwg64, 256, 0, stream>>>(x, w1Th, w1Tl, B0, N_NODES, F_IN, HC);
    al_kernel<4><<<N_NODES, 256, 0, stream>>>(B0, as1, ad1, als, ald);
    alpha_kernel<4><<<nblk_dst, 256, 0, stream>>>(als, ald, row_ptr, colidx, alpha);
    agg_v3<256, 64, 4, true, true><<<4 * nblk_dst, 256, 0, stream>>>(
        B0, alpha, row_ptr, colidx, b1, B1h, B1l, nullptr);
    // ---- layer 2 ----
    gemm_mfma<64, 64, 4><<<nwg64, 256, 0, stream>>>(B1h, B1l, w2Th, w2Tl, B0, N_NODES, HC, HC);
    al_kernel<4><<<N_NODES, 256, 0, stream>>>(B0, as2, ad2, als, ald);
    alpha_kernel<4><<<nblk_dst, 256, 0, stream>>>(als, ald, row_ptr, colidx, alpha);
    agg_v3<256, 64, 4, true, true><<<4 * nblk_dst, 256, 0, stream>>>(
        B0, alpha, row_ptr, colidx, b2, B1h, B1l, nullptr);
    // ---- layer 3 (H=1, C=64) ----
    const int nwg3 = (N_NODES + 63) / 64;                    // 313
    gemm_mfma<64, 64, 1><<<nwg3, 256, 0, stream>>>(B1h, B1l, w3Th, w3Tl, B0, N_NODES, HC, 64);
    al_kernel<1><<<N_NODES, 64, 0, stream>>>(B0, as3, ad3, als, ald);
    alpha_kernel<1><<<nblk_dst, 256, 0, stream>>>(als, ald, row_ptr, colidx, alpha);
    agg_v3<64, 64, 1, false, false><<<nblk_dst, 256, 0, stream>>>(
        B0, alpha, row_ptr, colidx, b3, nullptr, nullptr, B1f);
    // ---- classifier ----
    classifier_kernel<<<(N_NODES + 255) / 256, 256, 0, stream>>>(B1f, wc, bc, out);
}

// Round 10
// 311.253 us; speedup vs baseline: 1.1666x; 1.0182x over previous
//
#include <hip/hip_runtime.h>

#define N_NODES 20000
#define N_EDGES 320000
#define ET (N_EDGES + N_NODES)   // 340000 edges incl self-loops
#define F_IN 1024
#define HC 256                   // H*C for layers 1,2
#define NC 4

typedef unsigned short ushort_t;
typedef __attribute__((ext_vector_type(8))) short short8;
typedef __attribute__((ext_vector_type(4))) float f32x4;

// bf16 <-> f32 via bit ops (RTNE)
__device__ inline ushort_t f2bf(float f) {
    unsigned u = __float_as_uint(f);
    unsigned r = (u + 0x7fffu + ((u >> 16) & 1u)) >> 16;
    return (ushort_t)r;
}
__device__ inline float bf2f(ushort_t u) {
    return __uint_as_float(((unsigned)u) << 16);
}

// packed f32x2 -> bf16x2 (lo in bits 15:0, hi in bits 31:16), HW RTNE
__device__ inline unsigned cvt_pk_bf16(float lo, float hi) {
    unsigned r;
    asm("v_cvt_pk_bf16_f32 %0, %1, %2" : "=v"(r) : "v"(lo), "v"(hi));
    return r;
}

#define GLOAD16(gp, lp) __builtin_amdgcn_global_load_lds( \
    (const __attribute__((address_space(1))) void*)(gp),  \
    (__attribute__((address_space(3))) void*)(lp), 16, 0, 0)

// ---------------- CSR build ----------------
__global__ void count_kernel(const int* __restrict__ ei, int* __restrict__ counts) {
    int e = blockIdx.x * blockDim.x + threadIdx.x;
    if (e >= ET) return;
    int dst = (e < N_EDGES) ? ei[N_EDGES + e] : (e - N_EDGES);
    atomicAdd(&counts[dst], 1);
}

__global__ void scan_kernel(const int* __restrict__ counts, int* __restrict__ row_ptr,
                            int* __restrict__ cursor) {
    __shared__ int sums[1024];
    int t = threadIdx.x;
    const int per = (N_NODES + 1023) / 1024;
    int b = t * per;
    int e = min(b + per, N_NODES);
    int s = 0;
    for (int i = b; i < e; ++i) s += counts[i];
    sums[t] = s;
    __syncthreads();
    for (int off = 1; off < 1024; off <<= 1) {
        int v = (t >= off) ? sums[t - off] : 0;
        __syncthreads();
        sums[t] += v;
        __syncthreads();
    }
    int run = (t == 0) ? 0 : sums[t - 1];
    for (int i = b; i < e; ++i) {
        row_ptr[i] = run;
        cursor[i]  = run;
        run += counts[i];
    }
    if (t == 0) row_ptr[N_NODES] = ET;
}

__global__ void scatter_kernel(const int* __restrict__ ei, int* __restrict__ cursor,
                               int* __restrict__ col) {
    int e = blockIdx.x * blockDim.x + threadIdx.x;
    if (e >= ET) return;
    int src, dst;
    if (e < N_EDGES) { src = ei[e]; dst = ei[N_EDGES + e]; }
    else             { src = dst = e - N_EDGES; }
    int pos = atomicAdd(&cursor[dst], 1);
    col[pos] = src;
}

// weights: in [K][Nn] fp32 row-major -> hi/lo W^T [Nn][K] bf16
__global__ void split_T(const float* __restrict__ in, ushort_t* __restrict__ hi,
                        ushort_t* __restrict__ lo, int K, int Nn) {
    int idx = blockIdx.x * blockDim.x + threadIdx.x;
    if (idx >= K * Nn) return;
    int k = idx / Nn, n = idx - k * Nn;
    float v = in[idx];
    ushort_t h = f2bf(v);
    hi[(size_t)n * K + k] = h;
    lo[(size_t)n * K + k] = f2bf(v - bf2f(h));
}

// ---------------- GEMM1: fp32 A, cvt_pk split + prefetched A, 64x64 tile ----------------
template<int GY>
__launch_bounds__(256)
__global__ void gemm_f32a(const float* __restrict__ X,
                          const ushort_t* __restrict__ BTh, const ushort_t* __restrict__ BTl,
                          float* __restrict__ C, int M, int K, int NT) {
    constexpr int BM = 64, BN = 64, SM = 32, SN = 32, MF = 2, NF = 2;
    __shared__ __align__(16) ushort_t smem[4 * 64 * 32];
    char* Ash = (char*)smem;                  // 4096 B each
    char* Asl = Ash + 64 * 64;
    char* Bsh = Asl + 64 * 64;
    char* Bsl = Bsh + 64 * 64;

    const int t = threadIdx.x, lane = t & 63, w = t >> 6;
    const int wm = w >> 1, wn = w & 1;
    const int nwg = gridDim.x;
    const int id = blockIdx.x;
    const int q = nwg >> 3, r = nwg & 7;
    const int xcd = id & 7, idx = id >> 3;
    const int logical = (xcd < r ? xcd * (q + 1) : r * (q + 1) + (xcd - r) * q) + idx;
    const int bm = (logical / GY) * BM, bn = (logical % GY) * BN;

    // A staging geometry: row = w*16 + lane>>2 (64 rows), chunk = lane&3 (8 fp32)
    const int arow = w * 16 + (lane >> 2);
    const int achk = lane & 3;
    const int grow = min(bm + arow, M - 1);
    const float* xRow = X + (size_t)grow * K + achk * 8;
    const int aoff = arow * 64 + ((achk ^ ((arow >> 1) & 3)) * 16);

    // B staging (gload_lds, pre-swizzled source)
    const int gchunk = ((lane & 3) ^ ((lane >> 3) & 3)) * 16;
    const int brow = w * 16 + (lane >> 2);
    size_t gB = (size_t)(bn + brow) * K * 2 + gchunk;
    int lB = w * 1024;

    f32x4 acc[MF][NF];
    #pragma unroll
    for (int i = 0; i < MF; ++i)
        #pragma unroll
        for (int j = 0; j < NF; ++j) acc[i][j] = (f32x4){0.f, 0.f, 0.f, 0.f};

    const char* Bhb = (const char*)BTh;
    const char* Blb = (const char*)BTl;
    const int c16 = (lane >> 4);

    float4 c0 = *(const float4*)(xRow);
    float4 c1 = *(const float4*)(xRow + 4);
    for (int k0 = 0; k0 < K; k0 += 32) {
        // prefetch next K-step's A (hides L2/L3 latency under this step's MFMA)
        float4 n0, n1;
        if (k0 + 32 < K) {
            n0 = *(const float4*)(xRow + k0 + 32);
            n1 = *(const float4*)(xRow + k0 + 36);
        }
        // convert current A regs: packed bf16 hi + residual lo
        float vv[8] = {c0.x, c0.y, c0.z, c0.w, c1.x, c1.y, c1.z, c1.w};
        unsigned hp[4], lp[4];
        #pragma unroll
        for (int j = 0; j < 4; ++j) {
            unsigned h = cvt_pk_bf16(vv[2 * j], vv[2 * j + 1]);
            float h0 = __uint_as_float(h << 16);
            float h1 = __uint_as_float(h & 0xFFFF0000u);
            hp[j] = h;
            lp[j] = cvt_pk_bf16(vv[2 * j] - h0, vv[2 * j + 1] - h1);
        }
        *(uint4*)(Ash + aoff) = make_uint4(hp[0], hp[1], hp[2], hp[3]);
        *(uint4*)(Asl + aoff) = make_uint4(lp[0], lp[1], lp[2], lp[3]);
        // B: async to LDS
        size_t kb = (size_t)k0 * 2;
        GLOAD16(Bhb + gB + kb, Bsh + lB);
        GLOAD16(Blb + gB + kb, Bsl + lB);
        __syncthreads();
        short8 afh[MF], afl[MF], bfh[NF], bfl[NF];
        #pragma unroll
        for (int i = 0; i < MF; ++i) {
            int row = wm * SM + i * 16 + (lane & 15);
            int off = row * 64 + ((c16 ^ ((row >> 1) & 3)) * 16);
            afh[i] = *(const short8*)(Ash + off);
            afl[i] = *(const short8*)(Asl + off);
        }
        #pragma unroll
        for (int j = 0; j < NF; ++j) {
            int row = wn * SN + j * 16 + (lane & 15);
            int off = row * 64 + ((c16 ^ ((row >> 1) & 3)) * 16);
            bfh[j] = *(const short8*)(Bsh + off);
            bfl[j] = *(const short8*)(Bsl + off);
        }
        #pragma unroll
        for (int i = 0; i < MF; ++i)
            #pragma unroll
            for (int j = 0; j < NF; ++j) {
                acc[i][j] = __builtin_amdgcn_mfma_f32_16x16x32_bf16(afh[i], bfh[j], acc[i][j], 0, 0, 0);
                acc[i][j] = __builtin_amdgcn_mfma_f32_16x16x32_bf16(afh[i], bfl[j], acc[i][j], 0, 0, 0);
                acc[i][j] = __builtin_amdgcn_mfma_f32_16x16x32_bf16(afl[i], bfh[j], acc[i][j], 0, 0, 0);
            }
        __syncthreads();
        c0 = n0; c1 = n1;
    }
    #pragma unroll
    for (int i = 0; i < MF; ++i) {
        int rbase = bm + wm * SM + i * 16 + (lane >> 4) * 4;
        #pragma unroll
        for (int j = 0; j < NF; ++j) {
            int col = bn + wn * SN + j * 16 + (lane & 15);
            #pragma unroll
            for (int rr = 0; rr < 4; ++rr)
                if (rbase + rr < M) C[(size_t)(rbase + rr) * NT + col] = acc[i][j][rr];
        }
    }
}

// ---------------- fused split-bf16 MFMA GEMM (bf16 A), XCD-swizzled 1D grid ----------------
template<int BM, int BN, int GY>
__launch_bounds__(256)
__global__ void gemm_mfma(const ushort_t* __restrict__ Ah, const ushort_t* __restrict__ Al,
                          const ushort_t* __restrict__ BTh, const ushort_t* __restrict__ BTl,
                          float* __restrict__ C, int M, int K, int NT) {
    constexpr int SM = BM / 2;
    constexpr int SN = BN / 2;
    constexpr int MF = SM / 16;
    constexpr int NF = SN / 16;
    constexpr int AQ = BM / 64;
    constexpr int BQ = BN / 64;
    __shared__ __align__(16) ushort_t smem[(2 * BM + 2 * BN) * 32];
    char* Ash = (char*)smem;
    char* Asl = Ash + BM * 64;
    char* Bsh = Asl + BM * 64;
    char* Bsl = Bsh + BN * 64;

    const int t = threadIdx.x, lane = t & 63, w = t >> 6;
    const int wm = w >> 1, wn = w & 1;
    const int nwg = gridDim.x;
    const int id = blockIdx.x;
    const int q = nwg >> 3, r = nwg & 7;
    const int xcd = id & 7, idx = id >> 3;
    const int logical = (xcd < r ? xcd * (q + 1) : r * (q + 1) + (xcd - r) * q) + idx;
    const int bm = (logical / GY) * BM, bn = (logical % GY) * BN;
    const int gchunk = ((lane & 3) ^ ((lane >> 3) & 3)) * 16;  // pre-swizzled source

    size_t gA[AQ]; int lA[AQ];
    #pragma unroll
    for (int qq = 0; qq < AQ; ++qq) {
        int inst = w * AQ + qq;
        int row  = inst * 16 + (lane >> 2);
        int grow = min(bm + row, M - 1);
        gA[qq] = (size_t)grow * K * 2 + gchunk;
        lA[qq] = inst * 1024;
    }
    size_t gB[BQ]; int lB[BQ];
    #pragma unroll
    for (int qq = 0; qq < BQ; ++qq) {
        int inst = w * BQ + qq;
        int row  = inst * 16 + (lane >> 2);
        gB[qq] = (size_t)(bn + row) * K * 2 + gchunk;
        lB[qq] = inst * 1024;
    }

    f32x4 acc[MF][NF];
    #pragma unroll
    for (int i = 0; i < MF; ++i)
        #pragma unroll
        for (int j = 0; j < NF; ++j) acc[i][j] = (f32x4){0.f, 0.f, 0.f, 0.f};

    const char* Ahb = (const char*)Ah;
    const char* Alb = (const char*)Al;
    const char* Bhb = (const char*)BTh;
    const char* Blb = (const char*)BTl;
    const int c16 = (lane >> 4);

    for (int k0 = 0; k0 < K; k0 += 32) {
        size_t kb = (size_t)k0 * 2;
        #pragma unroll
        for (int qq = 0; qq < AQ; ++qq) {
            GLOAD16(Ahb + gA[qq] + kb, Ash + lA[qq]);
            GLOAD16(Alb + gA[qq] + kb, Asl + lA[qq]);
        }
        #pragma unroll
        for (int qq = 0; qq < BQ; ++qq) {
            GLOAD16(Bhb + gB[qq] + kb, Bsh + lB[qq]);
            GLOAD16(Blb + gB[qq] + kb, Bsl + lB[qq]);
        }
        __syncthreads();
        short8 afh[MF], afl[MF], bfh[NF], bfl[NF];
        #pragma unroll
        for (int i = 0; i < MF; ++i) {
            int row = wm * SM + i * 16 + (lane & 15);
            int off = row * 64 + ((c16 ^ ((row >> 1) & 3)) * 16);
            afh[i] = *(const short8*)(Ash + off);
            afl[i] = *(const short8*)(Asl + off);
        }
        #pragma unroll
        for (int j = 0; j < NF; ++j) {
            int row = wn * SN + j * 16 + (lane & 15);
            int off = row * 64 + ((c16 ^ ((row >> 1) & 3)) * 16);
            bfh[j] = *(const short8*)(Bsh + off);
            bfl[j] = *(const short8*)(Bsl + off);
        }
        #pragma unroll
        for (int i = 0; i < MF; ++i)
            #pragma unroll
            for (int j = 0; j < NF; ++j) {
                acc[i][j] = __builtin_amdgcn_mfma_f32_16x16x32_bf16(afh[i], bfh[j], acc[i][j], 0, 0, 0);
                acc[i][j] = __builtin_amdgcn_mfma_f32_16x16x32_bf16(afh[i], bfl[j], acc[i][j], 0, 0, 0);
                acc[i][j] = __builtin_amdgcn_mfma_f32_16x16x32_bf16(afl[i], bfh[j], acc[i][j], 0, 0, 0);
            }
        __syncthreads();
    }
    #pragma unroll
    for (int i = 0; i < MF; ++i) {
        int rbase = bm + wm * SM + i * 16 + (lane >> 4) * 4;
        #pragma unroll
        for (int j = 0; j < NF; ++j) {
            int col = bn + wn * SN + j * 16 + (lane & 15);
            #pragma unroll
            for (int rr = 0; rr < 4; ++rr)
                if (rbase + rr < M) C[(size_t)(rbase + rr) * NT + col] = acc[i][j][rr];
        }
    }
}

// ---------------- attention logits ----------------
template<int H>
__global__ void al_kernel(const float* __restrict__ h, const float* __restrict__ as_w,
                          const float* __restrict__ ad_w, float* __restrict__ als,
                          float* __restrict__ ald) {
    int n = blockIdx.x;
    int t = threadIdx.x;
    float hv = h[(size_t)n * (H * 64) + t];
    float s = hv * as_w[t];
    float d = hv * ad_w[t];
    #pragma unroll
    for (int off = 32; off > 0; off >>= 1) {
        s += __shfl_down(s, off, 64);
        d += __shfl_down(d, off, 64);
    }
    if ((t & 63) == 0) {
        int head = t >> 6;
        als[n * H + head] = s;
        ald[n * H + head] = d;
    }
}

// ---------------- alpha precompute: segment softmax -> alpha[H][ET] ----------------
template<int H>
__launch_bounds__(256)
__global__ void alpha_kernel(const float* __restrict__ als, const float* __restrict__ ald,
                             const int* __restrict__ row_ptr, const int* __restrict__ col,
                             float* __restrict__ alpha) {
    int lane = threadIdx.x & 63, w = threadIdx.x >> 6;
    int dst = blockIdx.x * 4 + w;
    if (dst >= N_NODES) return;
    int beg = row_ptr[dst], deg = row_ptr[dst + 1] - beg;
    constexpr int ES = 64 / H;
    int i_loc = lane / H, hh = lane % H;
    float ad = ald[dst * H + hh];
    float m = -1e30f, den = 0.f;
    for (int base = 0; base < deg; base += ES) {
        int i = base + i_loc;
        if (i < deg) {
            float e = als[col[beg + i] * H + hh] + ad;
            e = (e > 0.f) ? e : 0.2f * e;
            float nm = fmaxf(m, e);
            den = den * __expf(m - nm) + __expf(e - nm);
            m = nm;
        }
    }
    #pragma unroll
    for (int off = H; off < 64; off <<= 1) {
        float mo = __shfl_xor(m, off, 64);
        float dn = __shfl_xor(den, off, 64);
        float nm = fmaxf(m, mo);
        den = den * __expf(m - nm) + dn * __expf(mo - nm);
        m = nm;
    }
    float rden = 1.f / (den + 1e-16f);
    for (int base = 0; base < deg; base += ES) {
        int i = base + i_loc;
        if (i < deg) {
            float e = als[col[beg + i] * H + hh] + ad;
            e = (e > 0.f) ? e : 0.2f * e;
            alpha[(size_t)hh * ET + beg + i] = __expf(e - m) * rden;
        }
    }
}

// ---------------- channel-sliced aggregation v3 (LDS broadcast) ----------------
template<int CT, int CW, int H, bool RELU, bool SPLIT>
__launch_bounds__(256)
__global__ void agg_v3(const float* __restrict__ h, const float* __restrict__ alpha,
                       const int* __restrict__ row_ptr, const int* __restrict__ col,
                       const float* __restrict__ bias,
                       ushort_t* __restrict__ oh, ushort_t* __restrict__ ol,
                       float* __restrict__ of) {
    constexpr int NS  = CT / CW;         // slices (== H)
    constexpr int LPT = CW / 4;          // lanes per team (16)
    constexpr int TPW = 64 / LPT;        // teams / edges in flight per wave (4)
    static_assert(NS == H, "slice==head mapping");
    __shared__ int   s_src[4][64];
    __shared__ float s_alp[4][64];
    const int nwg = gridDim.x;           // NS * N/4, multiple of 8
    const int q = nwg >> 3;
    int id = blockIdx.x;
    int logical = (id & 7) * q + (id >> 3);
    int slice = logical / (N_NODES / 4);
    int g = logical - slice * (N_NODES / 4);
    int lane = threadIdx.x & 63, w = threadIdx.x >> 6;
    int dst = g * 4 + w;
    int beg = row_ptr[dst], deg = row_ptr[dst + 1] - beg;
    int team = lane / LPT;
    int cc = (lane & (LPT - 1)) * 4;     // channel quad within slice

    const int*   colP = col + beg;
    const float* aP   = alpha + (size_t)slice * ET + beg;
    const float* hS   = h + slice * CW + cc;

    float4 acc = make_float4(0.f, 0.f, 0.f, 0.f);
    for (int base = 0; base < deg; base += 64) {
        int cnt = min(64, deg - base);
        if (lane < cnt) {
            s_src[w][lane] = colP[base + lane];
            s_alp[w][lane] = aP[base + lane];
        }
        for (int i = team; i < cnt; i += TPW) {
            int   s = s_src[w][i];
            float a = s_alp[w][i];
            float4 hv = *(const float4*)&hS[s * CT];     // 32-bit addr math
            acc.x += a * hv.x; acc.y += a * hv.y;
            acc.z += a * hv.z; acc.w += a * hv.w;
        }
    }
    #pragma unroll
    for (int off = LPT; off < 64; off <<= 1) {
        acc.x += __shfl_xor(acc.x, off, 64);
        acc.y += __shfl_xor(acc.y, off, 64);
        acc.z += __shfl_xor(acc.z, off, 64);
        acc.w += __shfl_xor(acc.w, off, 64);
    }
    if (team == 0) {
        int ch = slice * CW + cc;
        float4 bv = *(const float4*)&bias[ch];
        float v0 = acc.x + bv.x, v1 = acc.y + bv.y, v2 = acc.z + bv.z, v3 = acc.w + bv.w;
        if (RELU) {
            v0 = fmaxf(v0, 0.f); v1 = fmaxf(v1, 0.f);
            v2 = fmaxf(v2, 0.f); v3 = fmaxf(v3, 0.f);
        }
        size_t idx = (size_t)dst * CT + ch;
        if (SPLIT) {
            ushort4 h4, l4;
            h4.x = f2bf(v0); l4.x = f2bf(v0 - bf2f(h4.x));
            h4.y = f2bf(v1); l4.y = f2bf(v1 - bf2f(h4.y));
            h4.z = f2bf(v2); l4.z = f2bf(v2 - bf2f(h4.z));
            h4.w = f2bf(v3); l4.w = f2bf(v3 - bf2f(h4.w));
            *(ushort4*)&oh[idx] = h4;
            *(ushort4*)&ol[idx] = l4;
        } else {
            *(float4*)&of[idx] = make_float4(v0, v1, v2, v3);
        }
    }
}

// ---------------- classifier ----------------
__global__ void classifier_kernel(const float* __restrict__ x, const float* __restrict__ wc,
                                  const float* __restrict__ bc, float* __restrict__ out) {
    int n = blockIdx.x * blockDim.x + threadIdx.x;
    if (n >= N_NODES) return;
    float acc[NC] = {bc[0], bc[1], bc[2], bc[3]};
    for (int c = 0; c < 64; ++c) {
        float xv = x[(size_t)n * 64 + c];
        #pragma unroll
        for (int k = 0; k < NC; ++k) acc[k] += xv * wc[c * NC + k];
    }
    #pragma unroll
    for (int k = 0; k < NC; ++k) out[(size_t)n * NC + k] = acc[k];
}

extern "C" void kernel_launch(void* const* d_in, const int* in_sizes, int n_in,
                              void* d_out, int out_size, void* d_ws, size_t ws_size,
                              hipStream_t stream) {
    const float* x   = (const float*)d_in[0];
    const int*   ei  = (const int*)d_in[1];
    const float* w1  = (const float*)d_in[2];
    const float* as1 = (const float*)d_in[3];
    const float* ad1 = (const float*)d_in[4];
    const float* b1  = (const float*)d_in[5];
    const float* w2  = (const float*)d_in[6];
    const float* as2 = (const float*)d_in[7];
    const float* ad2 = (const float*)d_in[8];
    const float* b2  = (const float*)d_in[9];
    const float* w3  = (const float*)d_in[10];
    const float* as3 = (const float*)d_in[11];
    const float* ad3 = (const float*)d_in[12];
    const float* b3  = (const float*)d_in[13];
    const float* wc  = (const float*)d_in[14];
    const float* bc  = (const float*)d_in[15];
    float* out = (float*)d_out;

    char* ws = (char*)d_ws;
    size_t off = 0;
    auto alloc = [&](size_t bytes) -> char* {
        char* p = ws + off;
        off = (off + bytes + 255) & ~(size_t)255;
        return p;
    };

    int* counts  = (int*)alloc(N_NODES * 4);
    int* cursor  = (int*)alloc(N_NODES * 4);
    int* row_ptr = (int*)alloc((N_NODES + 1) * 4);
    int* colidx  = (int*)alloc(ET * 4);
    float* als   = (float*)alloc(N_NODES * 4 * 4);
    float* ald   = (float*)alloc(N_NODES * 4 * 4);
    float* alpha = (float*)alloc((size_t)4 * ET * 4);        // [H][ET]
    float* B0    = (float*)alloc((size_t)N_NODES * HC * 4);

    ushort_t* w1Th = (ushort_t*)alloc((size_t)F_IN * HC * 2);
    ushort_t* w1Tl = (ushort_t*)alloc((size_t)F_IN * HC * 2);
    ushort_t* w2Th = (ushort_t*)alloc((size_t)HC * HC * 2);
    ushort_t* w2Tl = (ushort_t*)alloc((size_t)HC * HC * 2);
    ushort_t* w3Th = (ushort_t*)alloc((size_t)HC * 64 * 2);
    ushort_t* w3Tl = (ushort_t*)alloc((size_t)HC * 64 * 2);
    ushort_t* B1h  = (ushort_t*)alloc((size_t)N_NODES * HC * 2);
    ushort_t* B1l  = (ushort_t*)alloc((size_t)N_NODES * HC * 2);
    float*    B1f  = (float*)alloc((size_t)N_NODES * 64 * 4);

    // ---- CSR build ----
    hipMemsetAsync(counts, 0, N_NODES * sizeof(int), stream);
    int eb = (ET + 255) / 256;
    count_kernel<<<eb, 256, 0, stream>>>(ei, counts);
    scan_kernel<<<1, 1024, 0, stream>>>(counts, row_ptr, cursor);
    scatter_kernel<<<eb, 256, 0, stream>>>(ei, cursor, colidx);

    // ---- weight precision split ----
    split_T<<<(F_IN * HC + 255) / 256, 256, 0, stream>>>(w1, w1Th, w1Tl, F_IN, HC);
    split_T<<<(HC * HC + 255) / 256, 256, 0, stream>>>(w2, w2Th, w2Tl, HC, HC);
    split_T<<<(HC * 64 + 255) / 256, 256, 0, stream>>>(w3, w3Th, w3Tl, HC, 64);

    const int nwg64 = ((N_NODES + 63) / 64) * (HC / 64);     // 313*4 = 1252
    const int nblk_dst = N_NODES / 4;                        // 5000
    // ---- layer 1 (fp32 A, on-the-fly cvt_pk split) ----
    gemm_f32a<4><<<nwg64, 256, 0, stream>>>(x, w1Th, w1Tl, B0, N_NODES, F_IN, HC);
    al_kernel<4><<<N_NODES, 256, 0, stream>>>(B0, as1, ad1, als, ald);
    alpha_kernel<4><<<nblk_dst, 256, 0, stream>>>(als, ald, row_ptr, colidx, alpha);
    agg_v3<256, 64, 4, true, true><<<4 * nblk_dst, 256, 0, stream>>>(
        B0, alpha, row_ptr, colidx, b1, B1h, B1l, nullptr);
    // ---- layer 2 ----
    gemm_mfma<64, 64, 4><<<nwg64, 256, 0, stream>>>(B1h, B1l, w2Th, w2Tl, B0, N_NODES, HC, HC);
    al_kernel<4><<<N_NODES, 256, 0, stream>>>(B0, as2, ad2, als, ald);
    alpha_kernel<4><<<nblk_dst, 256, 0, stream>>>(als, ald, row_ptr, colidx, alpha);
    agg_v3<256, 64, 4, true, true><<<4 * nblk_dst, 256, 0, stream>>>(
        B0, alpha, row_ptr, colidx, b2, B1h, B1l, nullptr);
    // ---- layer 3 (H=1, C=64) ----
    const int nwg3 = (N_NODES + 63) / 64;                    // 313
    gemm_mfma<64, 64, 1><<<nwg3, 256, 0, stream>>>(B1h, B1l, w3Th, w3Tl, B0, N_NODES, HC, 64);
    al_kernel<1><<<N_NODES, 64, 0, stream>>>(B0, as3, ad3, als, ald);
    alpha_kernel<1><<<nblk_dst, 256, 0, stream>>>(als, ald, row_ptr, colidx, alpha);
    agg_v3<64, 64, 1, false, false><<<nblk_dst, 256, 0, stream>>>(
        B0, alpha, row_ptr, colidx, b3, nullptr, nullptr, B1f);
    // ---- classifier ----
    classifier_kernel<<<(N_NODES + 255) / 256, 256, 0, stream>>>(B1f, wc, bc, out);
}